// Round 4
// baseline (190.354 us; speedup 1.0000x reference)
//
#include <hip/hip_runtime.h>
#include <math.h>

// Softmax over last dim. x: (2,16,2048,2048) fp32 -> out fp32, same shape.
// 65536 rows of 2048 floats. One wave (64 lanes) per row-group of 4 rows;
// software-pipelined: prefetch row r+1 (8 x nt dwordx4) while computing
// row r, so the HBM queue never drains during the exp/reduce phase.

#define ROW_LEN       2048
#define CHUNKS        8      // per lane per row: (2048/4) / 64
#define ROWS_PER_WAVE 4

typedef float f32x4 __attribute__((ext_vector_type(4)));

__device__ __forceinline__ void load_row(const float* __restrict__ rowp,
                                         int lane, f32x4* buf) {
    const f32x4* __restrict__ p = reinterpret_cast<const f32x4*>(rowp);
#pragma unroll
    for (int k = 0; k < CHUNKS; ++k)
        buf[k] = __builtin_nontemporal_load(&p[lane + 64 * k]);
}

__device__ __forceinline__ void compute_store_row(float* __restrict__ rowp,
                                                  int lane, f32x4* v) {
    // ---- row max ----
    float m = -INFINITY;
#pragma unroll
    for (int k = 0; k < CHUNKS; ++k)
        m = fmaxf(m, fmaxf(fmaxf(v[k].x, v[k].y), fmaxf(v[k].z, v[k].w)));
#pragma unroll
    for (int off = 32; off >= 1; off >>= 1)
        m = fmaxf(m, __shfl_xor(m, off, 64));

    // ---- exp + row sum ----
    float s = 0.f;
#pragma unroll
    for (int k = 0; k < CHUNKS; ++k) {
        v[k].x = __expf(v[k].x - m);
        v[k].y = __expf(v[k].y - m);
        v[k].z = __expf(v[k].z - m);
        v[k].w = __expf(v[k].w - m);
        s += (v[k].x + v[k].y) + (v[k].z + v[k].w);
    }
#pragma unroll
    for (int off = 32; off >= 1; off >>= 1)
        s += __shfl_xor(s, off, 64);

    const float inv = 1.0f / s;

    f32x4* __restrict__ p = reinterpret_cast<f32x4*>(rowp);
#pragma unroll
    for (int k = 0; k < CHUNKS; ++k) {
        f32x4 t = v[k] * inv;
        __builtin_nontemporal_store(t, &p[lane + 64 * k]);
    }
}

__global__ __launch_bounds__(256, 4) void softmax_row_kernel(
        const float* __restrict__ x, float* __restrict__ out, int nrows) {
    const int wave = threadIdx.x >> 6;   // 0..3
    const int lane = threadIdx.x & 63;
    const long long row0 = ((long long)blockIdx.x * 4 + wave) * ROWS_PER_WAVE;
    if (row0 >= nrows) return;

    const float* __restrict__ xbase = x + (size_t)row0 * ROW_LEN;
    float* __restrict__ obase = out + (size_t)row0 * ROW_LEN;

    f32x4 A[CHUNKS], B[CHUNKS];

    // prologue: load row 0
    load_row(xbase, lane, A);

#pragma unroll
    for (int r = 0; r < ROWS_PER_WAVE; ++r) {
        f32x4* cur = (r & 1) ? B : A;
        f32x4* nxt = (r & 1) ? A : B;
        if (r < ROWS_PER_WAVE - 1)
            load_row(xbase + (size_t)(r + 1) * ROW_LEN, lane, nxt);  // prefetch
        compute_store_row(obase + (size_t)r * ROW_LEN, lane, cur);
    }
}

extern "C" void kernel_launch(void* const* d_in, const int* in_sizes, int n_in,
                              void* d_out, int out_size, void* d_ws, size_t ws_size,
                              hipStream_t stream) {
    const float* x = (const float*)d_in[0];
    float* out = (float*)d_out;
    const int nrows = in_sizes[0] / ROW_LEN;                 // 65536
    const int waves = (nrows + ROWS_PER_WAVE - 1) / ROWS_PER_WAVE;
    const int blocks = (waves + 3) / 4;                      // 4 waves per block
    softmax_row_kernel<<<blocks, 256, 0, stream>>>(x, out, nrows);
}